// Round 1
// baseline (3751.445 us; speedup 1.0000x reference)
//
#include <hip/hip_runtime.h>

// ---------------------------------------------------------------------------
// M3GNet forward, fp32. Sizes (fixed by problem): N=8000 atoms, E=200000
// edges, A=400000 angles, NG=100 graphs, FD=128. N%32==0, E%64==0 assumed.
// Key algebraic restructurings vs reference:
//   gate(angle)      -> per-ATOM G = sigmoid(v@Wg+bg), gathered per angle
//   [vi,vj,e]@W(384) -> P1[send]+P2[recv]+e@W[256:384]  (per-atom precompute)
// ---------------------------------------------------------------------------

__device__ __forceinline__ float sigmoidf_(float x) { return 1.0f / (1.0f + __expf(-x)); }
__device__ __forceinline__ float swishf_(float x) { return x * sigmoidf_(x); }

__device__ __forceinline__ float4 f4add(float4 a, float4 b) {
    return make_float4(a.x + b.x, a.y + b.y, a.z + b.z, a.w + b.w);
}
__device__ __forceinline__ float4 f4mul(float4 a, float4 b) {
    return make_float4(a.x * b.x, a.y * b.y, a.z * b.z, a.w * b.w);
}
__device__ __forceinline__ float4 f4swish(float4 a) {
    return make_float4(swishf_(a.x), swishf_(a.y), swishf_(a.z), swishf_(a.w));
}
__device__ __forceinline__ float4 f4sig(float4 a) {
    return make_float4(sigmoidf_(a.x), sigmoidf_(a.y), sigmoidf_(a.z), sigmoidf_(a.w));
}
__device__ __forceinline__ float4 f4scale(float4 a, float s) {
    return make_float4(a.x * s, a.y * s, a.z * s, a.w * s);
}
__device__ __forceinline__ float4 f4fmas(float4 a, float s, float4 c) {
    return make_float4(fmaf(a.x, s, c.x), fmaf(a.y, s, c.y), fmaf(a.z, s, c.z), fmaf(a.w, s, c.w));
}
__device__ __forceinline__ float4 f4fma(float4 a, float4 b, float4 c) {
    return make_float4(fmaf(a.x, b.x, c.x), fmaf(a.y, b.y, c.y), fmaf(a.z, b.z, c.z), fmaf(a.w, b.w, c.w));
}
__device__ __forceinline__ float getc(const float4& v, int i) {
    return i == 0 ? v.x : (i == 1 ? v.y : (i == 2 ? v.z : v.w));
}

#define FMA4(J, A) \
    acc[J].x = fmaf(A, bv.x, acc[J].x); acc[J].y = fmaf(A, bv.y, acc[J].y); \
    acc[J].z = fmaf(A, bv.z, acc[J].z); acc[J].w = fmaf(A, bv.w, acc[J].w)

// C[64 x 128] += At[128 x 64 (stride S)]^T-style GEMM. acc: 8 m-rows x 4 f.
template <int S>
__device__ __forceinline__ void gemm64(const float* As, const float* __restrict__ B,
                                       int tm, int f0, float4 acc[8]) {
#pragma unroll 4
    for (int k = 0; k < 128; ++k) {
        const float* ap = As + k * S + (tm << 3);
        const float4 a0 = *(const float4*)ap;
        const float4 a1 = *(const float4*)(ap + 4);
        const float4 bv = *(const float4*)(B + (k << 7) + f0);
        FMA4(0, a0.x); FMA4(1, a0.y); FMA4(2, a0.z); FMA4(3, a0.w);
        FMA4(4, a1.x); FMA4(5, a1.y); FMA4(6, a1.z); FMA4(7, a1.w);
    }
}

// C[32 x 128]: acc: 4 m-rows x 4 f.
template <int S>
__device__ __forceinline__ void gemm32(const float* As, const float* __restrict__ B,
                                       int tm, int f0, float4 acc[4]) {
#pragma unroll 4
    for (int k = 0; k < 128; ++k) {
        const float4 a0 = *(const float4*)(As + k * S + (tm << 2));
        const float4 bv = *(const float4*)(B + (k << 7) + f0);
        FMA4(0, a0.x); FMA4(1, a0.y); FMA4(2, a0.z); FMA4(3, a0.w);
    }
}

// write er[8 m][4 f] transposed into At[k=f][m], row stride 68 (reads 2-way/free)
__device__ __forceinline__ void storeT68(float* At, const float4 er[8], int tm, int f0) {
#pragma unroll
    for (int i = 0; i < 4; ++i) {
        float4 w0, w1;
        w0.x = getc(er[0], i); w0.y = getc(er[1], i); w0.z = getc(er[2], i); w0.w = getc(er[3], i);
        w1.x = getc(er[4], i); w1.y = getc(er[5], i); w1.z = getc(er[6], i); w1.w = getc(er[7], i);
        float* p = At + (f0 + i) * 68 + (tm << 3);
        *(float4*)p = w0;
        *(float4*)(p + 4) = w1;
    }
}

// ---------------------------------------------------------------------------
__global__ void k_offsets(const int* __restrict__ tnb, const int* __restrict__ tna,
                          int NG, int* __restrict__ boff, int* __restrict__ acum) {
    if (threadIdx.x == 0 && blockIdx.x == 0) {
        int ab = 0, aa = 0;
        for (int g = 0; g < NG; ++g) {
            boff[g] = ab;
            ab += tnb[g];
            aa += tna[g];
            acum[g] = aa;
        }
    }
}

__global__ void k_angle_setup(const int* __restrict__ tb, const float* __restrict__ rnorm,
                              const float* __restrict__ cosang, const int* __restrict__ ei,
                              int E, int A, int NG,
                              const int* __restrict__ boff, const int* __restrict__ acum,
                              float* __restrict__ ang, float* __restrict__ fcik,
                              int* __restrict__ kat, int* __restrict__ iij) {
    const int a = blockIdx.x * 256 + threadIdx.x;
    if (a >= A) return;
    int lo = 0, hi = NG - 1;
    while (lo < hi) {
        const int mid = (lo + hi) >> 1;
        if (a < acum[mid]) hi = mid; else lo = mid + 1;
    }
    const int off = boff[lo];
    const int ij = tb[2 * a] + off;
    const int ik = tb[2 * a + 1] + off;
    iij[a] = ij;
    kat[a] = ei[(size_t)E + ik];  // recv[idx_ik]

    const float r = rnorm[a], c = cosang[a];
    const float rinv = 1.0f / r;
    const float x = r * 0.25f;
    const float fc = 1.0f + x * x * x * (-10.0f + x * (15.0f - 6.0f * x));
    const float p2 = 1.5f * c * c - 0.5f;
    const float p3 = 2.5f * c * c * c - 1.5f * c;
    float4* ap = (float4*)(ang + (size_t)a * 16);
#pragma unroll
    for (int n = 0; n < 4; ++n) {
        const float rad = __sinf(r * (float)(n + 1) * 0.7853981633974483f) * rinv * fc;
        ap[n] = make_float4(rad, rad * c, rad * p2, rad * p3);
    }
    fcik[a] = fc;
}

__global__ void k_edge_init(const float* __restrict__ dist, const float* __restrict__ Wenc,
                            const float* __restrict__ benc, float* __restrict__ e,
                            float* __restrict__ ef0, int E) {
    const size_t gid = (size_t)blockIdx.x * 256 + threadIdx.x;
    if (gid >= (size_t)E * 128) return;
    const int edge = (int)(gid >> 7), f = (int)(gid & 127);
    const float r = dist[edge];
    const float rinv = 1.0f / r;
    float s[5];
#pragma unroll
    for (int n = 0; n < 5; ++n)
        s[n] = 0.6324555320336759f * __sinf(r * (float)(n + 1) * 0.6283185307179586f) * rinv;
    float acc = benc[f];
#pragma unroll
    for (int n = 0; n < 5; ++n) acc = fmaf(s[n], Wenc[n * 128 + f], acc);
    e[gid] = swishf_(acc);
    if (f < 5) ef0[(size_t)edge * 5 + f] = s[f];
}

__global__ void k_atom_init(const int* __restrict__ an, const float* __restrict__ emb,
                            float* __restrict__ v, int N) {
    const size_t gid = (size_t)blockIdx.x * 256 + threadIdx.x;
    if (gid >= (size_t)N * 128) return;
    v[gid] = emb[(size_t)an[gid >> 7] * 128 + (gid & 127)];
}

// Per-atom: G = sigmoid(v@Wg+bg), Pe1=v@We1[0:128], Pe2=v@We1[128:256],
// Pa1=v@Wa1[0:128], Pa2=v@Wa1[128:256].  32-atom tiles.
__global__ void k_atom_pre(const float* __restrict__ v,
                           const float* __restrict__ Wg, const float* __restrict__ bg,
                           const float* __restrict__ We1b, const float* __restrict__ Wa1b,
                           float* __restrict__ G, float* __restrict__ Pe1, float* __restrict__ Pe2,
                           float* __restrict__ Pa1, float* __restrict__ Pa2) {
    __shared__ float At[128 * 32];
    const int t = threadIdx.x;
    const int tn = t & 31, tm = t >> 5;
    const int f0 = tn << 2;
    const size_t base = (size_t)blockIdx.x * 32;
    {
        const int m = t & 31, cb = t >> 5;
        const float4* src = (const float4*)(v + (base + m) * 128);
#pragma unroll
        for (int i = 0; i < 4; ++i) {
            const int c = cb + (i << 3);
            const float4 ld = src[c];
            float* dst = At + (c << 2) * 32 + m;
            dst[0] = ld.x; dst[32] = ld.y; dst[64] = ld.z; dst[96] = ld.w;
        }
    }
    __syncthreads();
#define ATOM_GEMM(Bptr, OUT, DO_SIG)                                              \
    {                                                                             \
        float4 acc[4] = {};                                                       \
        gemm32<32>(At, (Bptr), tm, f0, acc);                                      \
        if (DO_SIG) {                                                             \
            const float4 bgv = *(const float4*)(bg + f0);                         \
            _Pragma("unroll") for (int j = 0; j < 4; ++j)                         \
                acc[j] = f4sig(f4add(acc[j], bgv));                               \
        }                                                                         \
        _Pragma("unroll") for (int j = 0; j < 4; ++j)                             \
            *(float4*)((OUT) + (base + (tm << 2) + j) * 128 + f0) = acc[j];       \
    }
    ATOM_GEMM(Wg, G, 1)
    ATOM_GEMM(We1b, Pe1, 0)
    ATOM_GEMM(We1b + 16384, Pe2, 0)
    ATOM_GEMM(Wa1b, Pa1, 0)
    ATOM_GEMM(Wa1b + 16384, Pa2, 0)
#undef ATOM_GEMM
}

// Per-angle message into agg (atomic). One thread per (angle, feature).
__global__ void k_angle(const float* __restrict__ ang, const float* __restrict__ fcik,
                        const int* __restrict__ kat, const int* __restrict__ iij,
                        const float* __restrict__ G, const float* __restrict__ Wang,
                        float* __restrict__ agg, int A) {
    const size_t gid = (size_t)blockIdx.x * 256 + threadIdx.x;
    if (gid >= (size_t)A * 128) return;
    const int a = (int)(gid >> 7);
    const int f = (int)(gid & 127);
    const float4* av = (const float4*)(ang + (size_t)a * 16);
    const float4 a0 = av[0], a1 = av[1], a2 = av[2], a3 = av[3];
    float acc = a0.x * Wang[f];
    acc = fmaf(a0.y, Wang[128 + f], acc);
    acc = fmaf(a0.z, Wang[256 + f], acc);
    acc = fmaf(a0.w, Wang[384 + f], acc);
    acc = fmaf(a1.x, Wang[512 + f], acc);
    acc = fmaf(a1.y, Wang[640 + f], acc);
    acc = fmaf(a1.z, Wang[768 + f], acc);
    acc = fmaf(a1.w, Wang[896 + f], acc);
    acc = fmaf(a2.x, Wang[1024 + f], acc);
    acc = fmaf(a2.y, Wang[1152 + f], acc);
    acc = fmaf(a2.z, Wang[1280 + f], acc);
    acc = fmaf(a2.w, Wang[1408 + f], acc);
    acc = fmaf(a3.x, Wang[1536 + f], acc);
    acc = fmaf(a3.y, Wang[1664 + f], acc);
    acc = fmaf(a3.z, Wang[1792 + f], acc);
    acc = fmaf(a3.w, Wang[1920 + f], acc);
    const float val = acc * G[(size_t)kat[a] * 128 + f] * fcik[a];
    atomicAdd(agg + (size_t)iij[a] * 128 + f, val);
}

// Fused per-edge kernel: 64-edge tiles, three K=128 GEMMs.
__global__ void k_edge(float* __restrict__ e, const float* __restrict__ agg,
                       const int* __restrict__ ei, int E,
                       const float* __restrict__ Pe1, const float* __restrict__ Pe2,
                       const float* __restrict__ Pa1, const float* __restrict__ Pa2,
                       const float* __restrict__ ef0,
                       const float* __restrict__ Wtb, const float* __restrict__ btb,
                       const float* __restrict__ We1e, const float* __restrict__ be1,
                       const float* __restrict__ We0,
                       const float* __restrict__ Wa1e, const float* __restrict__ ba1,
                       const float* __restrict__ Wa0, float* __restrict__ dv) {
    __shared__ float At[128 * 68];
    __shared__ int sidx[128];      // send[0:64], recv[64:128]
    __shared__ float sef0[320];

    const int t = threadIdx.x;
    const int tn = t & 31, tm = t >> 5;
    const int f0 = tn << 2;
    const size_t base = (size_t)blockIdx.x * 64;

    if (t < 64) {
        sidx[t] = ei[base + t];
        sidx[64 + t] = ei[(size_t)E + base + t];
    }
    for (int idx = t; idx < 320; idx += 256) sef0[idx] = ef0[base * 5 + idx];

    {   // agg tile -> At (k-major, stride 64); store pattern 2-way (free)
        const int m = t & 63, cb = t >> 6;
        const float4* src = (const float4*)(agg + (base + m) * 128);
#pragma unroll
        for (int i = 0; i < 8; ++i) {
            const int c = cb + (i << 2);
            const float4 ld = src[c];
            float* dst = At + (c << 2) * 64 + m;
            dst[0] = ld.x; dst[64] = ld.y; dst[128] = ld.z; dst[192] = ld.w;
        }
    }
    float4 er[8];
#pragma unroll
    for (int j = 0; j < 8; ++j)
        er[j] = *(const float4*)(e + (base + (tm << 3) + j) * 128 + f0);
    __syncthreads();

    // ---- GEMM1: e += swish(agg @ W_tb + b_tb)
    float4 acc[8] = {};
    gemm64<64>(At, Wtb, tm, f0, acc);
    {
        const float4 bt = *(const float4*)(btb + f0);
#pragma unroll
        for (int j = 0; j < 8; ++j)
            er[j] = f4add(er[j], f4swish(f4add(acc[j], bt)));
    }
    __syncthreads();
    storeT68(At, er, tm, f0);
    __syncthreads();

    // ---- GEMM2: e += swish(P1[send]+P2[recv]+e@We1[256:]+be1) * (ef0@We0)
#pragma unroll
    for (int j = 0; j < 8; ++j) acc[j] = make_float4(0.f, 0.f, 0.f, 0.f);
    gemm64<68>(At, We1e, tm, f0, acc);
    {
        const float4 be = *(const float4*)(be1 + f0);
        float4 wc[5];
#pragma unroll
        for (int n = 0; n < 5; ++n) wc[n] = *(const float4*)(We0 + n * 128 + f0);
#pragma unroll
        for (int j = 0; j < 8; ++j) {
            const int m = (tm << 3) + j;
            const float4 p1 = *(const float4*)(Pe1 + (size_t)sidx[m] * 128 + f0);
            const float4 p2 = *(const float4*)(Pe2 + (size_t)sidx[64 + m] * 128 + f0);
            const float4 x = f4add(f4add(acc[j], be), f4add(p1, p2));
            const float* ef = sef0 + m * 5;
            float4 sc = f4scale(wc[0], ef[0]);
            sc = f4fmas(wc[1], ef[1], sc);
            sc = f4fmas(wc[2], ef[2], sc);
            sc = f4fmas(wc[3], ef[3], sc);
            sc = f4fmas(wc[4], ef[4], sc);
            er[j] = f4fma(f4swish(x), sc, er[j]);
        }
    }
#pragma unroll
    for (int j = 0; j < 8; ++j)
        *(float4*)(e + (base + (tm << 3) + j) * 128 + f0) = er[j];
    __syncthreads();
    storeT68(At, er, tm, f0);
    __syncthreads();

    // ---- GEMM3: m = swish(P1+P2+e@Wa1[256:]+ba1)*(ef0@Wa0); dv[recv] += m
#pragma unroll
    for (int j = 0; j < 8; ++j) acc[j] = make_float4(0.f, 0.f, 0.f, 0.f);
    gemm64<68>(At, Wa1e, tm, f0, acc);
    {
        const float4 ba = *(const float4*)(ba1 + f0);
        float4 wc[5];
#pragma unroll
        for (int n = 0; n < 5; ++n) wc[n] = *(const float4*)(Wa0 + n * 128 + f0);
#pragma unroll
        for (int j = 0; j < 8; ++j) {
            const int m = (tm << 3) + j;
            const int rr = sidx[64 + m];
            const float4 p1 = *(const float4*)(Pa1 + (size_t)sidx[m] * 128 + f0);
            const float4 p2 = *(const float4*)(Pa2 + (size_t)rr * 128 + f0);
            const float4 x = f4add(f4add(acc[j], ba), f4add(p1, p2));
            const float* ef = sef0 + m * 5;
            float4 sc = f4scale(wc[0], ef[0]);
            sc = f4fmas(wc[1], ef[1], sc);
            sc = f4fmas(wc[2], ef[2], sc);
            sc = f4fmas(wc[3], ef[3], sc);
            sc = f4fmas(wc[4], ef[4], sc);
            const float4 mv = f4mul(f4swish(x), sc);
            float* d = dv + (size_t)rr * 128 + f0;
            atomicAdd(d + 0, mv.x);
            atomicAdd(d + 1, mv.y);
            atomicAdd(d + 2, mv.z);
            atomicAdd(d + 3, mv.w);
        }
    }
}

__global__ void k_vupd(float* __restrict__ v, const float* __restrict__ dv, int n) {
    const int i = blockIdx.x * 256 + threadIdx.x;
    if (i < n) v[i] += dv[i];
}

// out = (swish(swish(v@W1+b1)@W2+b2)) @ W3 + b3.  32-atom tiles.
__global__ void k_readout(const float* __restrict__ v,
                          const float* __restrict__ W1, const float* __restrict__ b1,
                          const float* __restrict__ W2, const float* __restrict__ b2,
                          const float* __restrict__ W3, const float* __restrict__ b3,
                          float* __restrict__ out) {
    __shared__ float At[128 * 36];
    const int t = threadIdx.x;
    const int tn = t & 31, tm = t >> 5;
    const int f0 = tn << 2;
    const size_t base = (size_t)blockIdx.x * 32;
    {
        const int m = t & 31, cb = t >> 5;
        const float4* src = (const float4*)(v + (base + m) * 128);
#pragma unroll
        for (int i = 0; i < 4; ++i) {
            const int c = cb + (i << 3);
            const float4 ld = src[c];
            float* dst = At + (c << 2) * 32 + m;
            dst[0] = ld.x; dst[32] = ld.y; dst[64] = ld.z; dst[96] = ld.w;
        }
    }
    __syncthreads();
    float4 acc[4] = {};
    gemm32<32>(At, W1, tm, f0, acc);
    {
        const float4 bv1 = *(const float4*)(b1 + f0);
#pragma unroll
        for (int j = 0; j < 4; ++j) acc[j] = f4swish(f4add(acc[j], bv1));
    }
    __syncthreads();
#pragma unroll
    for (int i = 0; i < 4; ++i) {
        float4 w0;
        w0.x = getc(acc[0], i); w0.y = getc(acc[1], i); w0.z = getc(acc[2], i); w0.w = getc(acc[3], i);
        *(float4*)(At + (f0 + i) * 36 + (tm << 2)) = w0;
    }
    __syncthreads();
    float4 acc2[4] = {};
    gemm32<36>(At, W2, tm, f0, acc2);
    const float4 bv2 = *(const float4*)(b2 + f0);
    const float4 w3v = *(const float4*)(W3 + f0);
#pragma unroll
    for (int j = 0; j < 4; ++j) {
        const float4 h = f4swish(f4add(acc2[j], bv2));
        float p = h.x * w3v.x + h.y * w3v.y + h.z * w3v.z + h.w * w3v.w;
        p += __shfl_xor(p, 16);
        p += __shfl_xor(p, 8);
        p += __shfl_xor(p, 4);
        p += __shfl_xor(p, 2);
        p += __shfl_xor(p, 1);
        if (tn == 0) out[base + (tm << 2) + j] = p + b3[0];
    }
}

// ---------------------------------------------------------------------------
extern "C" void kernel_launch(void* const* d_in, const int* in_sizes, int n_in,
                              void* d_out, int out_size, void* d_ws, size_t ws_size,
                              hipStream_t stream) {
    const int N = in_sizes[0];
    const int E = in_sizes[2];
    const int A = in_sizes[4];
    const int NG = in_sizes[6];

    const int* an = (const int*)d_in[0];
    const int* ei = (const int*)d_in[1];
    const float* dist = (const float*)d_in[2];
    const int* tb = (const int*)d_in[3];
    const float* rnorm = (const float*)d_in[4];
    const float* cosang = (const float*)d_in[5];
    const int* tnb = (const int*)d_in[6];
    const int* tna = (const int*)d_in[7];
    const float* emb = (const float*)d_in[8];
    const float* Wenc = (const float*)d_in[9];
    const float* benc = (const float*)d_in[10];
    const float* Wang = (const float*)d_in[11];
    const float* Wg = (const float*)d_in[12];
    const float* bg = (const float*)d_in[13];
    const float* Wtb = (const float*)d_in[14];
    const float* btb = (const float*)d_in[15];
    const float* We1 = (const float*)d_in[16];
    const float* be1 = (const float*)d_in[17];
    const float* We0 = (const float*)d_in[18];
    const float* Wa1 = (const float*)d_in[19];
    const float* ba1 = (const float*)d_in[20];
    const float* Wa0 = (const float*)d_in[21];
    const float* W1 = (const float*)d_in[22];
    const float* b1 = (const float*)d_in[23];
    const float* W2 = (const float*)d_in[24];
    const float* b2 = (const float*)d_in[25];
    const float* W3 = (const float*)d_in[26];
    const float* b3 = (const float*)d_in[27];
    float* out = (float*)d_out;

    float* ws = (float*)d_ws;
    size_t off = 0;
    auto alloc = [&](size_t n) { float* p = ws + off; off += (n + 3) & ~(size_t)3; return p; };
    float* e_ = alloc((size_t)E * 128);
    float* agg = alloc((size_t)E * 128);
    float* v_ = alloc((size_t)N * 128);
    float* dv = alloc((size_t)N * 128);
    float* G = alloc((size_t)N * 128);
    float* Pe1 = alloc((size_t)N * 128);
    float* Pe2 = alloc((size_t)N * 128);
    float* Pa1 = alloc((size_t)N * 128);
    float* Pa2 = alloc((size_t)N * 128);
    float* ef0 = alloc((size_t)E * 5);
    float* angf = alloc((size_t)A * 16);
    float* fcik = alloc((size_t)A);
    int* kat = (int*)alloc((size_t)A);
    int* iij = (int*)alloc((size_t)A);
    int* boff = (int*)alloc(256);
    int* acum = boff + 128;

    k_offsets<<<1, 64, 0, stream>>>(tnb, tna, NG, boff, acum);
    k_angle_setup<<<(A + 255) / 256, 256, 0, stream>>>(tb, rnorm, cosang, ei, E, A, NG,
                                                       boff, acum, angf, fcik, kat, iij);
    k_edge_init<<<(int)(((size_t)E * 128 + 255) / 256), 256, 0, stream>>>(dist, Wenc, benc, e_, ef0, E);
    k_atom_init<<<(int)(((size_t)N * 128 + 255) / 256), 256, 0, stream>>>(an, emb, v_, N);

    for (int b = 0; b < 4; ++b) {
        (void)hipMemsetAsync(agg, 0, (size_t)E * 128 * sizeof(float), stream);
        (void)hipMemsetAsync(dv, 0, (size_t)N * 128 * sizeof(float), stream);
        k_atom_pre<<<N / 32, 256, 0, stream>>>(v_, Wg + (size_t)b * 16384, bg + b * 128,
                                               We1 + (size_t)b * 49152, Wa1 + (size_t)b * 49152,
                                               G, Pe1, Pe2, Pa1, Pa2);
        k_angle<<<(int)(((size_t)A * 128 + 255) / 256), 256, 0, stream>>>(
            angf, fcik, kat, iij, G, Wang + (size_t)b * 2048, agg, A);
        k_edge<<<E / 64, 256, 0, stream>>>(e_, agg, ei, E, Pe1, Pe2, Pa1, Pa2, ef0,
                                           Wtb + (size_t)b * 16384, btb + b * 128,
                                           We1 + (size_t)b * 49152 + 32768, be1 + b * 128,
                                           We0 + (size_t)b * 640,
                                           Wa1 + (size_t)b * 49152 + 32768, ba1 + b * 128,
                                           Wa0 + (size_t)b * 640, dv);
        k_vupd<<<(int)(((size_t)N * 128 + 255) / 256), 256, 0, stream>>>(v_, dv, N * 128);
    }
    k_readout<<<N / 32, 256, 0, stream>>>(v_, W1, b1, W2, b2, W3, b3, out);
}

// Round 2
// 1867.225 us; speedup vs baseline: 2.0091x; 2.0091x over previous
//
#include <hip/hip_runtime.h>

// ---------------------------------------------------------------------------
// M3GNet forward. N=8000, E=200000, A=400000, NG=100, FD=128.
// Round 2: bf16-MFMA edge GEMMs + angle CSR (no agg atomics) + D-layout e.
// ---------------------------------------------------------------------------

typedef short short8 __attribute__((ext_vector_type(8)));
typedef float f32x4v __attribute__((ext_vector_type(4)));

__device__ __forceinline__ float sigmoidf_(float x) { return 1.0f / (1.0f + __expf(-x)); }
__device__ __forceinline__ float swishf_(float x) { return x * sigmoidf_(x); }

__device__ __forceinline__ unsigned short f2bf(float x) {
    unsigned int u = __float_as_uint(x);
    unsigned int r = (u + 0x7FFFu + ((u >> 16) & 1u)) >> 16;
    return (unsigned short)r;
}

__device__ __forceinline__ f32x4v mfma_bf16(short8 a, short8 b, f32x4v c) {
    return __builtin_amdgcn_mfma_f32_16x16x32_bf16(a, b, c, 0, 0, 0);
}

__device__ __forceinline__ float4 f4add(float4 a, float4 b) {
    return make_float4(a.x + b.x, a.y + b.y, a.z + b.z, a.w + b.w);
}
__device__ __forceinline__ float4 f4swish(float4 a) {
    return make_float4(swishf_(a.x), swishf_(a.y), swishf_(a.z), swishf_(a.w));
}
__device__ __forceinline__ float4 f4sig(float4 a) {
    return make_float4(sigmoidf_(a.x), sigmoidf_(a.y), sigmoidf_(a.z), sigmoidf_(a.w));
}
__device__ __forceinline__ float getc(const float4& v, int i) {
    return i == 0 ? v.x : (i == 1 ? v.y : (i == 2 ? v.z : v.w));
}

#define FMA4(J, A) \
    acc[J].x = fmaf(A, bv.x, acc[J].x); acc[J].y = fmaf(A, bv.y, acc[J].y); \
    acc[J].z = fmaf(A, bv.z, acc[J].z); acc[J].w = fmaf(A, bv.w, acc[J].w)

template <int S>
__device__ __forceinline__ void gemm32(const float* As, const float* __restrict__ B,
                                       int tm, int f0, float4 acc[4]) {
#pragma unroll 4
    for (int k = 0; k < 128; ++k) {
        const float4 a0 = *(const float4*)(As + k * S + (tm << 2));
        const float4 bv = *(const float4*)(B + (k << 7) + f0);
        FMA4(0, a0.x); FMA4(1, a0.y); FMA4(2, a0.z); FMA4(3, a0.w);
    }
}

// ---------------------------------------------------------------------------
__global__ void k_offsets(const int* __restrict__ tnb, const int* __restrict__ tna,
                          int NG, int* __restrict__ boff, int* __restrict__ acum) {
    if (threadIdx.x == 0 && blockIdx.x == 0) {
        int ab = 0, aa = 0;
        for (int g = 0; g < NG; ++g) {
            boff[g] = ab;
            ab += tnb[g];
            aa += tna[g];
            acum[g] = aa;
        }
    }
}

// per-angle: features, fc, kat, iij; histogram on iij.
__global__ void k_angle_setup(const int* __restrict__ tb, const float* __restrict__ rnorm,
                              const float* __restrict__ cosang, const int* __restrict__ ei,
                              int E, int A, int NG,
                              const int* __restrict__ boff, const int* __restrict__ acum,
                              float* __restrict__ ang, float* __restrict__ fcik,
                              int* __restrict__ kat, int* __restrict__ iij,
                              int* __restrict__ cnt) {
    const int a = blockIdx.x * 256 + threadIdx.x;
    if (a >= A) return;
    int lo = 0, hi = NG - 1;
    while (lo < hi) {
        const int mid = (lo + hi) >> 1;
        if (a < acum[mid]) hi = mid; else lo = mid + 1;
    }
    const int off = boff[lo];
    const int ij = tb[2 * a] + off;
    const int ik = tb[2 * a + 1] + off;
    iij[a] = ij;
    kat[a] = ei[(size_t)E + ik];
    atomicAdd(&cnt[ij], 1);

    const float r = rnorm[a], c = cosang[a];
    const float rinv = 1.0f / r;
    const float x = r * 0.25f;
    const float fc = 1.0f + x * x * x * (-10.0f + x * (15.0f - 6.0f * x));
    const float p2 = 1.5f * c * c - 0.5f;
    const float p3 = 2.5f * c * c * c - 1.5f * c;
    float4* ap = (float4*)(ang + (size_t)a * 16);
#pragma unroll
    for (int n = 0; n < 4; ++n) {
        const float rad = __sinf(r * (float)(n + 1) * 0.7853981633974483f) * rinv * fc;
        ap[n] = make_float4(rad, rad * c, rad * p2, rad * p3);
    }
    fcik[a] = fc;
}

// two-level exclusive scan over cnt[E] -> start[E]
__global__ void k_scan1(const int* __restrict__ cnt, int* __restrict__ start,
                        int* __restrict__ bsum, int E) {
    __shared__ int sh[256];
    const int t = threadIdx.x;
    const int base = blockIdx.x * 2048 + t * 8;
    int v[8], s = 0;
#pragma unroll
    for (int i = 0; i < 8; ++i) { v[i] = (base + i < E) ? cnt[base + i] : 0; s += v[i]; }
    sh[t] = s;
    __syncthreads();
    for (int off = 1; off < 256; off <<= 1) {
        int x = (t >= off) ? sh[t - off] : 0;
        __syncthreads();
        sh[t] += x;
        __syncthreads();
    }
    if (t == 255) bsum[blockIdx.x] = sh[255];
    int run = sh[t] - s;
#pragma unroll
    for (int i = 0; i < 8; ++i) { if (base + i < E) start[base + i] = run; run += v[i]; }
}

__global__ void k_scan2(int* __restrict__ bsum, int nb) {
    __shared__ int sh[256];
    const int t = threadIdx.x;
    int v = (t < nb) ? bsum[t] : 0;
    sh[t] = v;
    __syncthreads();
    for (int off = 1; off < 256; off <<= 1) {
        int x = (t >= off) ? sh[t - off] : 0;
        __syncthreads();
        sh[t] += x;
        __syncthreads();
    }
    if (t < nb) bsum[t] = sh[t] - v;
}

__global__ void k_scan3(int* __restrict__ start, const int* __restrict__ bsum, int E) {
    const int i = blockIdx.x * 256 + threadIdx.x;
    if (i < E) start[i] += bsum[i >> 11];
}

// scatter angle payload into CSR order; fold fc (2nd cutoff factor) into ang.
__global__ void k_scatter(const float* __restrict__ ang, const float* __restrict__ fcik,
                          const int* __restrict__ kat, const int* __restrict__ iij,
                          const int* __restrict__ start, int* __restrict__ fill,
                          float* __restrict__ angS, int* __restrict__ katS, int A) {
    const int a = blockIdx.x * 256 + threadIdx.x;
    if (a >= A) return;
    const int ij = iij[a];
    const int pos = start[ij] + atomicAdd(&fill[ij], 1);
    const float fc = fcik[a];
    const float4* src = (const float4*)(ang + (size_t)a * 16);
    float4* dst = (float4*)(angS + (size_t)pos * 16);
#pragma unroll
    for (int j = 0; j < 4; ++j) {
        float4 v = src[j];
        dst[j] = make_float4(v.x * fc, v.y * fc, v.z * fc, v.w * fc);
    }
    katS[pos] = kat[a];
}

// pack 12 weight matrices (4 layers x {Wtb, We1[256:], Wa1[256:]}) into
// MFMA B-frag layout: Bpk[mat][(kc*8+nt)*64+lane][j] bf16, j=0..7.
__global__ void k_pack(const float* __restrict__ Wtb, const float* __restrict__ We1,
                       const float* __restrict__ Wa1, unsigned short* __restrict__ Bpk) {
    const int gid = blockIdx.x * 256 + threadIdx.x;  // 0..24575
    const int mat = gid >> 11;
    const int t2 = gid & 2047;
    const int b = mat / 3, which = mat % 3;
    const float* W = (which == 0) ? (Wtb + (size_t)b * 16384)
                   : (which == 1) ? (We1 + (size_t)b * 49152 + 32768)
                                  : (Wa1 + (size_t)b * 49152 + 32768);
    const int kc = t2 >> 9, nt = (t2 >> 6) & 7, lane = t2 & 63;
    const int q = lane >> 4, cc = lane & 15;
    const int col = nt * 16 + cc;
    union { unsigned short us[8]; uint4 v; } pk;
#pragma unroll
    for (int j = 0; j < 8; ++j)
        pk.us[j] = f2bf(W[(size_t)(kc * 32 + q * 8 + j) * 128 + col]);
    *(uint4*)(Bpk + (size_t)mat * 16384 + (size_t)((kc * 8 + nt) * 64 + lane) * 8) = pk.v;
}

// e init in D-layout eP[((strip*64+lane)*8+nt)*4+r]; also ef0[edge*5+n].
__global__ void k_edge_init(const float* __restrict__ dist, const float* __restrict__ Wenc,
                            const float* __restrict__ benc, float* __restrict__ eP,
                            float* __restrict__ ef0) {
    __shared__ float sarr[16][5];
    const int s = blockIdx.x, t = threadIdx.x;
    if (t < 16) {
        const float r = dist[s * 16 + t];
        const float rinv = 1.0f / r;
#pragma unroll
        for (int n = 0; n < 5; ++n) {
            const float v = 0.6324555320336759f * __sinf(r * (float)(n + 1) * 0.6283185307179586f) * rinv;
            sarr[t][n] = v;
            ef0[(size_t)(s * 16 + t) * 5 + n] = v;
        }
    }
    __syncthreads();
    const int lane = t >> 3, nt = t & 7;
    const int q = lane >> 4, c = lane & 15, f = nt * 16 + c;
    float wv[5];
#pragma unroll
    for (int n = 0; n < 5; ++n) wv[n] = Wenc[n * 128 + f];
    const float bz = benc[f];
    float4 o;
#pragma unroll
    for (int r = 0; r < 4; ++r) {
        const int m = q * 4 + r;
        float acc = bz;
#pragma unroll
        for (int n = 0; n < 5; ++n) acc = fmaf(sarr[m][n], wv[n], acc);
        (&o.x)[r] = swishf_(acc);
    }
    *(float4*)(eP + ((size_t)(s * 64 + lane) * 8 + nt) * 4) = o;
}

__global__ void k_atom_init(const int* __restrict__ an, const float* __restrict__ emb,
                            float* __restrict__ v, int N) {
    const size_t gid = (size_t)blockIdx.x * 256 + threadIdx.x;
    if (gid >= (size_t)N * 128) return;
    v[gid] = emb[(size_t)an[gid >> 7] * 128 + (gid & 127)];
}

// per-atom GEMMs; blockIdx.y selects {G, Pe1, Pe2, Pa1, Pa2}.
__global__ void k_atom_pre(const float* __restrict__ v,
                           const float* __restrict__ Wg, const float* __restrict__ bg,
                           const float* __restrict__ We1b, const float* __restrict__ Wa1b,
                           float* __restrict__ G, float* __restrict__ Pe1, float* __restrict__ Pe2,
                           float* __restrict__ Pa1, float* __restrict__ Pa2) {
    __shared__ float At[128 * 32];
    const int t = threadIdx.x;
    const int tn = t & 31, tm = t >> 5;
    const int f0 = tn << 2;
    const size_t base = (size_t)blockIdx.x * 32;
    {
        const int m = t & 31, cb = t >> 5;
        const float4* src = (const float4*)(v + (base + m) * 128);
#pragma unroll
        for (int i = 0; i < 4; ++i) {
            const int c = cb + (i << 3);
            const float4 ld = src[c];
            float* dst = At + (c << 2) * 32 + m;
            dst[0] = ld.x; dst[32] = ld.y; dst[64] = ld.z; dst[96] = ld.w;
        }
    }
    __syncthreads();
    const float* B;
    float* OUT;
    int dosig = 0;
    switch (blockIdx.y) {
        case 0: B = Wg; OUT = G; dosig = 1; break;
        case 1: B = We1b; OUT = Pe1; break;
        case 2: B = We1b + 16384; OUT = Pe2; break;
        case 3: B = Wa1b; OUT = Pa1; break;
        default: B = Wa1b + 16384; OUT = Pa2; break;
    }
    float4 acc[4] = {};
    gemm32<32>(At, B, tm, f0, acc);
    if (dosig) {
        const float4 bgv = *(const float4*)(bg + f0);
#pragma unroll
        for (int j = 0; j < 4; ++j) acc[j] = f4sig(f4add(acc[j], bgv));
    }
#pragma unroll
    for (int j = 0; j < 4; ++j)
        *(float4*)(OUT + (base + (tm << 2) + j) * 128 + f0) = acc[j];
}

// one wave per edge: agg[edge][f] = sum over its angles of (ang@Wang)*G[kat];
// writes bf16 row-major aggP[edge*128+f].
__global__ void k_agg(const float* __restrict__ angS, const int* __restrict__ katS,
                      const int* __restrict__ start, const int* __restrict__ cnt,
                      const float* __restrict__ G, const float* __restrict__ Wang,
                      unsigned int* __restrict__ aggP, int E) {
    const int w = threadIdx.x >> 6, l = threadIdx.x & 63;
    const int edge = blockIdx.x * 4 + w;
    if (edge >= E) return;
    float2 wc[16];
#pragma unroll
    for (int c = 0; c < 16; ++c) wc[c] = *(const float2*)(Wang + c * 128 + 2 * l);
    float a0 = 0.0f, a1 = 0.0f;
    const int s0 = start[edge], n = cnt[edge];
    for (int t = 0; t < n; ++t) {
        const float4* ap = (const float4*)(angS + (size_t)(s0 + t) * 16);
        const float4 A0 = ap[0], A1 = ap[1], A2 = ap[2], A3 = ap[3];
        const float2 gv = *(const float2*)(G + (size_t)katS[s0 + t] * 128 + 2 * l);
        float m0, m1;
        m0 = A0.x * wc[0].x;  m1 = A0.x * wc[0].y;
        m0 = fmaf(A0.y, wc[1].x, m0);  m1 = fmaf(A0.y, wc[1].y, m1);
        m0 = fmaf(A0.z, wc[2].x, m0);  m1 = fmaf(A0.z, wc[2].y, m1);
        m0 = fmaf(A0.w, wc[3].x, m0);  m1 = fmaf(A0.w, wc[3].y, m1);
        m0 = fmaf(A1.x, wc[4].x, m0);  m1 = fmaf(A1.x, wc[4].y, m1);
        m0 = fmaf(A1.y, wc[5].x, m0);  m1 = fmaf(A1.y, wc[5].y, m1);
        m0 = fmaf(A1.z, wc[6].x, m0);  m1 = fmaf(A1.z, wc[6].y, m1);
        m0 = fmaf(A1.w, wc[7].x, m0);  m1 = fmaf(A1.w, wc[7].y, m1);
        m0 = fmaf(A2.x, wc[8].x, m0);  m1 = fmaf(A2.x, wc[8].y, m1);
        m0 = fmaf(A2.y, wc[9].x, m0);  m1 = fmaf(A2.y, wc[9].y, m1);
        m0 = fmaf(A2.z, wc[10].x, m0); m1 = fmaf(A2.z, wc[10].y, m1);
        m0 = fmaf(A2.w, wc[11].x, m0); m1 = fmaf(A2.w, wc[11].y, m1);
        m0 = fmaf(A3.x, wc[12].x, m0); m1 = fmaf(A3.x, wc[12].y, m1);
        m0 = fmaf(A3.y, wc[13].x, m0); m1 = fmaf(A3.y, wc[13].y, m1);
        m0 = fmaf(A3.z, wc[14].x, m0); m1 = fmaf(A3.z, wc[14].y, m1);
        m0 = fmaf(A3.w, wc[15].x, m0); m1 = fmaf(A3.w, wc[15].y, m1);
        a0 = fmaf(m0, gv.x, a0);
        a1 = fmaf(m1, gv.y, a1);
    }
    aggP[(size_t)edge * 64 + l] = (unsigned int)f2bf(a0) | ((unsigned int)f2bf(a1) << 16);
}

// ---------------------------------------------------------------------------
// Fused per-edge MFMA kernel: 64 edges/block, 4 waves, wave w owns edges
// 16w..16w+15 (its own 16-row LDS slab -> only one cross-wave barrier).
__global__ void __launch_bounds__(256, 3) k_edge(
    const unsigned short* __restrict__ aggP, const float* __restrict__ ef0g,
    float* __restrict__ eP, const int* __restrict__ ei, int E,
    const float* __restrict__ Pe1, const float* __restrict__ Pe2,
    const float* __restrict__ Pa1, const float* __restrict__ Pa2,
    const unsigned short* __restrict__ Bpk3,
    const float* __restrict__ btb, const float* __restrict__ be1,
    const float* __restrict__ We0, const float* __restrict__ ba1,
    const float* __restrict__ Wa0, float* __restrict__ dv) {
    __shared__ __align__(16) unsigned short At[64 * 136];  // +8 bf16 pad per row
    __shared__ int sidx[128];
    __shared__ float sef0[320];

    const int t = threadIdx.x;
    const int w = t >> 6, l = t & 63;
    const int q = l >> 4, c = l & 15;
    const size_t base = (size_t)blockIdx.x * 64;

    if (t < 64) {
        sidx[t] = ei[base + t];
        sidx[64 + t] = ei[(size_t)E + base + t];
    }
    for (int i = t; i < 320; i += 256) sef0[i] = ef0g[base * 5 + i];
    {   // stage agg tile (bf16, row-major) -> At
        const short8* src = (const short8*)(aggP + base * 128);
#pragma unroll
        for (int i = 0; i < 4; ++i) {
            const int idx = i * 256 + t;
            const int m = idx >> 4, cc = (idx & 15) * 8;
            *(short8*)(At + m * 136 + cc) = src[idx];
        }
    }
    __syncthreads();

    const short8* Bp1 = (const short8*)Bpk3;
    const short8* Bp2 = Bp1 + 2048;
    const short8* Bp3 = Bp2 + 2048;
    const f32x4v zz = {0.0f, 0.0f, 0.0f, 0.0f};

    short8 af[4];
#define LOAD_AF                                                                  \
    _Pragma("unroll") for (int kc = 0; kc < 4; ++kc)                             \
        af[kc] = *(const short8*)(At + (16 * w + c) * 136 + kc * 32 + q * 8);

    // ---- GEMM1: agg @ Wtb
    LOAD_AF
    f32x4v acc[8];
#pragma unroll
    for (int nt = 0; nt < 8; ++nt) acc[nt] = zz;
#pragma unroll
    for (int nt = 0; nt < 8; ++nt)
#pragma unroll
        for (int kc = 0; kc < 4; ++kc)
            acc[nt] = mfma_bf16(af[kc], Bp1[(kc * 8 + nt) * 64 + l], acc[nt]);

    float* ePblk = eP + (((size_t)blockIdx.x * 4 + w) * 64 + l) * 32;
    f32x4v er[8];
#pragma unroll
    for (int nt = 0; nt < 8; ++nt) {
        const f32x4v eo = *(const f32x4v*)(ePblk + nt * 4);
        const float bt = btb[nt * 16 + c];
#pragma unroll
        for (int r = 0; r < 4; ++r) er[nt][r] = eo[r] + swishf_(acc[nt][r] + bt);
    }
    __syncthreads();
#pragma unroll
    for (int nt = 0; nt < 8; ++nt)
#pragma unroll
        for (int r = 0; r < 4; ++r)
            At[(16 * w + q * 4 + r) * 136 + nt * 16 + c] = f2bf(er[nt][r]);
    __syncthreads();

    // per-edge metadata for epilogues
    int ss[4], rr[4];
    float efs[4][5];
#pragma unroll
    for (int r = 0; r < 4; ++r) {
        const int m = 16 * w + q * 4 + r;
        ss[r] = sidx[m];
        rr[r] = sidx[64 + m];
#pragma unroll
        for (int n = 0; n < 5; ++n) efs[r][n] = sef0[m * 5 + n];
    }

    // ---- GEMM2: e @ We1[256:384]
    LOAD_AF
#pragma unroll
    for (int nt = 0; nt < 8; ++nt) acc[nt] = zz;
#pragma unroll
    for (int nt = 0; nt < 8; ++nt)
#pragma unroll
        for (int kc = 0; kc < 4; ++kc)
            acc[nt] = mfma_bf16(af[kc], Bp2[(kc * 8 + nt) * 64 + l], acc[nt]);
#pragma unroll
    for (int nt = 0; nt < 8; ++nt) {
        const int fo = nt * 16 + c;
        const float bt = be1[fo];
        const float w0 = We0[fo], w1 = We0[128 + fo], w2 = We0[256 + fo],
                    w3 = We0[384 + fo], w4 = We0[512 + fo];
#pragma unroll
        for (int r = 0; r < 4; ++r) {
            const float p1 = Pe1[(size_t)ss[r] * 128 + fo];
            const float p2 = Pe2[(size_t)rr[r] * 128 + fo];
            const float x = acc[nt][r] + bt + p1 + p2;
            float sc = efs[r][0] * w0;
            sc = fmaf(efs[r][1], w1, sc);
            sc = fmaf(efs[r][2], w2, sc);
            sc = fmaf(efs[r][3], w3, sc);
            sc = fmaf(efs[r][4], w4, sc);
            er[nt][r] += swishf_(x) * sc;
        }
        *(f32x4v*)(ePblk + nt * 4) = er[nt];
    }
    __syncthreads();
#pragma unroll
    for (int nt = 0; nt < 8; ++nt)
#pragma unroll
        for (int r = 0; r < 4; ++r)
            At[(16 * w + q * 4 + r) * 136 + nt * 16 + c] = f2bf(er[nt][r]);
    __syncthreads();

    // ---- GEMM3: e @ Wa1[256:384]; dv[recv] += m
    LOAD_AF
#pragma unroll
    for (int nt = 0; nt < 8; ++nt) acc[nt] = zz;
#pragma unroll
    for (int nt = 0; nt < 8; ++nt)
#pragma unroll
        for (int kc = 0; kc < 4; ++kc)
            acc[nt] = mfma_bf16(af[kc], Bp3[(kc * 8 + nt) * 64 + l], acc[nt]);
#pragma unroll
    for (int nt = 0; nt < 8; ++nt) {
        const int fo = nt * 16 + c;
        const float bt = ba1[fo];
        const float w0 = Wa0[fo], w1 = Wa0[128 + fo], w2 = Wa0[256 + fo],
                    w3 = Wa0[384 + fo], w4 = Wa0[512 + fo];
#pragma unroll
        for (int r = 0; r < 4; ++r) {
            const float p1 = Pa1[(size_t)ss[r] * 128 + fo];
            const float p2 = Pa2[(size_t)rr[r] * 128 + fo];
            const float x = acc[nt][r] + bt + p1 + p2;
            float sc = efs[r][0] * w0;
            sc = fmaf(efs[r][1], w1, sc);
            sc = fmaf(efs[r][2], w2, sc);
            sc = fmaf(efs[r][3], w3, sc);
            sc = fmaf(efs[r][4], w4, sc);
            atomicAdd(dv + (size_t)rr[r] * 128 + fo, swishf_(x) * sc);
        }
    }
#undef LOAD_AF
}

__global__ void k_vupd(float* __restrict__ v, const float* __restrict__ dv, int n) {
    const int i = blockIdx.x * 256 + threadIdx.x;
    if (i < n) v[i] += dv[i];
}

__global__ void k_readout(const float* __restrict__ v,
                          const float* __restrict__ W1, const float* __restrict__ b1,
                          const float* __restrict__ W2, const float* __restrict__ b2,
                          const float* __restrict__ W3, const float* __restrict__ b3,
                          float* __restrict__ out) {
    __shared__ float At[128 * 36];
    const int t = threadIdx.x;
    const int tn = t & 31, tm = t >> 5;
    const int f0 = tn << 2;
    const size_t base = (size_t)blockIdx.x * 32;
    {
        const int m = t & 31, cb = t >> 5;
        const float4* src = (const float4*)(v + (base + m) * 128);
#pragma unroll
        for (int i = 0; i < 4; ++i) {
            const int c = cb + (i << 3);
            const float4 ld = src[c];
            float* dst = At + (c << 2) * 32 + m;
            dst[0] = ld.x; dst[32] = ld.y; dst[64] = ld.z; dst[96] = ld.w;
        }
    }
    __syncthreads();
    float4 acc[4] = {};
    gemm32<32>(At, W1, tm, f0, acc);
    {
        const float4 bv1 = *(const float4*)(b1 + f0);
#pragma unroll
        for (int j = 0; j < 4; ++j) acc[j] = f4swish(f4add(acc[j], bv1));
    }
    __syncthreads();
#pragma unroll
    for (int i = 0; i < 4; ++i) {
        float4 w0;
        w0.x = getc(acc[0], i); w0.y = getc(acc[1], i); w0.z = getc(acc[2], i); w0.w = getc(acc[3], i);
        *(float4*)(At + (f0 + i) * 36 + (tm << 2)) = w0;
    }
    __syncthreads();
    float4 acc2[4] = {};
    gemm32<36>(At, W2, tm, f0, acc2);
    const float4 bv2 = *(const float4*)(b2 + f0);
    const float4 w3v = *(const float4*)(W3 + f0);
#pragma unroll
    for (int j = 0; j < 4; ++j) {
        const float4 h = f4swish(f4add(acc2[j], bv2));
        float p = h.x * w3v.x + h.y * w3v.y + h.z * w3v.z + h.w * w3v.w;
        p += __shfl_xor(p, 16);
        p += __shfl_xor(p, 8);
        p += __shfl_xor(p, 4);
        p += __shfl_xor(p, 2);
        p += __shfl_xor(p, 1);
        if (tn == 0) out[base + (tm << 2) + j] = p + b3[0];
    }
}

// ---------------------------------------------------------------------------
extern "C" void kernel_launch(void* const* d_in, const int* in_sizes, int n_in,
                              void* d_out, int out_size, void* d_ws, size_t ws_size,
                              hipStream_t stream) {
    const int N = in_sizes[0];
    const int E = in_sizes[2];
    const int A = in_sizes[4];
    const int NG = in_sizes[6];

    const int* an = (const int*)d_in[0];
    const int* ei = (const int*)d_in[1];
    const float* dist = (const float*)d_in[2];
    const int* tb = (const int*)d_in[3];
    const float* rnorm = (const float*)d_in[4];
    const float* cosang = (const float*)d_in[5];
    const int* tnb = (const int*)d_in[6];
    const int* tna = (const int*)d_in[7];
    const float* emb = (const float*)d_in[8];
    const float* Wenc = (const float*)d_in[9];
    const float* benc = (const float*)d_in[10];
    const float* Wang = (const float*)d_in[11];
    const float* Wg = (const float*)d_in[12];
    const float* bg = (const float*)d_in[13];
    const float* Wtb = (const float*)d_in[14];
    const float* btb = (const float*)d_in[15];
    const float* We1 = (const float*)d_in[16];
    const float* be1 = (const float*)d_in[17];
    const float* We0 = (const float*)d_in[18];
    const float* Wa1 = (const float*)d_in[19];
    const float* ba1 = (const float*)d_in[20];
    const float* Wa0 = (const float*)d_in[21];
    const float* W1 = (const float*)d_in[22];
    const float* b1 = (const float*)d_in[23];
    const float* W2 = (const float*)d_in[24];
    const float* b2 = (const float*)d_in[25];
    const float* W3 = (const float*)d_in[26];
    const float* b3 = (const float*)d_in[27];
    float* out = (float*)d_out;

    float* ws = (float*)d_ws;
    size_t off = 0;
    auto alloc = [&](size_t n) { float* p = ws + off; off += (n + 3) & ~(size_t)3; return p; };
    float* eP = alloc((size_t)E * 128);
    float* v_ = alloc((size_t)N * 128);
    float* dv = alloc((size_t)N * 128);
    float* G = alloc((size_t)N * 128);
    float* Pe1 = alloc((size_t)N * 128);
    float* Pe2 = alloc((size_t)N * 128);
    float* Pa1 = alloc((size_t)N * 128);
    float* Pa2 = alloc((size_t)N * 128);
    float* ef0 = alloc((size_t)E * 5);
    float* ang = alloc((size_t)A * 16);
    float* angS = alloc((size_t)A * 16);
    float* fcik = alloc((size_t)A);
    int* kat = (int*)alloc((size_t)A);
    int* katS = (int*)alloc((size_t)A);
    int* iij = (int*)alloc((size_t)A);
    int* cnt = (int*)alloc((size_t)E);
    int* start = (int*)alloc((size_t)E);
    int* fill = (int*)alloc((size_t)E);
    int* bsum = (int*)alloc(512);
    int* boff = (int*)alloc(256);
    int* acum = boff + 128;
    unsigned int* aggP = (unsigned int*)alloc((size_t)E * 64);       // E*128 bf16
    unsigned short* Bpk = (unsigned short*)alloc((size_t)12 * 8192); // 12*16384 bf16

    const int nscan = (E + 2047) / 2048;

    (void)hipMemsetAsync(cnt, 0, (size_t)E * 4, stream);
    (void)hipMemsetAsync(fill, 0, (size_t)E * 4, stream);
    k_offsets<<<1, 64, 0, stream>>>(tnb, tna, NG, boff, acum);
    k_angle_setup<<<(A + 255) / 256, 256, 0, stream>>>(tb, rnorm, cosang, ei, E, A, NG,
                                                       boff, acum, ang, fcik, kat, iij, cnt);
    k_scan1<<<nscan, 256, 0, stream>>>(cnt, start, bsum, E);
    k_scan2<<<1, 256, 0, stream>>>(bsum, nscan);
    k_scan3<<<(E + 255) / 256, 256, 0, stream>>>(start, bsum, E);
    k_scatter<<<(A + 255) / 256, 256, 0, stream>>>(ang, fcik, kat, iij, start, fill, angS, katS, A);
    k_pack<<<96, 256, 0, stream>>>(Wtb, We1, Wa1, Bpk);
    k_edge_init<<<E / 16, 512, 0, stream>>>(dist, Wenc, benc, eP, ef0);
    k_atom_init<<<(int)(((size_t)N * 128 + 255) / 256), 256, 0, stream>>>(an, emb, v_, N);

    for (int b = 0; b < 4; ++b) {
        (void)hipMemsetAsync(dv, 0, (size_t)N * 128 * sizeof(float), stream);
        k_atom_pre<<<dim3(N / 32, 5), 256, 0, stream>>>(
            v_, Wg + (size_t)b * 16384, bg + b * 128,
            We1 + (size_t)b * 49152, Wa1 + (size_t)b * 49152,
            G, Pe1, Pe2, Pa1, Pa2);
        k_agg<<<(E + 3) / 4, 256, 0, stream>>>(angS, katS, start, cnt, G,
                                               Wang + (size_t)b * 2048, aggP, E);
        k_edge<<<E / 64, 256, 0, stream>>>(
            (const unsigned short*)aggP, ef0, eP, ei, E, Pe1, Pe2, Pa1, Pa2,
            Bpk + (size_t)(b * 3) * 16384,
            btb + b * 128, be1 + b * 128, We0 + (size_t)b * 640,
            ba1 + b * 128, Wa0 + (size_t)b * 640, dv);
        k_vupd<<<(int)(((size_t)N * 128 + 255) / 256), 256, 0, stream>>>(v_, dv, N * 128);
    }
    k_readout<<<N / 32, 256, 0, stream>>>(v_, W1, b1, W2, b2, W3, b3, out);
}